// Round 7
// baseline (346.772 us; speedup 1.0000x reference)
//
#include <hip/hip_runtime.h>

#define SIGMA_INV 1.0e4f          // 1/SIGMA
#define GAMMA_INV 1.0e4f          // 1/GAMMA
#define ZNEAR 1.0f
#define ZFAR 100.0f
#define EPSV 1e-10f

constexpr int KF = 8;
constexpr int NPIX = 4 * 512 * 512;
constexpr int NFACES = 200000;

// native clang vector so __builtin_nontemporal_load accepts it
typedef unsigned uvec4 __attribute__((ext_vector_type(4)));

// ---------------------------------------------------------------------------
// Kernel 1: pack the 3 vertex normals of each face into ONE 16 B record.
// 9 components x 14-bit fixed point (126 bits). Half-step err 6.1e-5; the
// final rgb/||rgb|| normalize amplifies ~32x -> ~2e-3, under threshold.
// Table = 3.2 MB -> L2-resident per XCD (R4 FETCH_SIZE confirmed).
// ---------------------------------------------------------------------------
__global__ __launch_bounds__(256) void pack_face_normals14(
    const int*   __restrict__ faces,   // (F,3)
    const float* __restrict__ vnorm,   // (V,3)
    uvec4*       __restrict__ fn,      // (F) packed
    int F)
{
    const int f = blockIdx.x * blockDim.x + threadIdx.x;
    if (f >= F) return;
    const int v[3] = { faces[f * 3 + 0], faces[f * 3 + 1], faces[f * 3 + 2] };

    unsigned long long lo = 0ull, hi = 0ull;
    int i = 0;
#pragma unroll
    for (int t = 0; t < 3; ++t) {
#pragma unroll
        for (int c = 0; c < 3; ++c, ++i) {
            const float x = vnorm[(size_t)v[t] * 3 + c];
            const unsigned long long code = (unsigned long long)(unsigned)
                __float2int_rn(fminf(fmaxf(x, -1.0f), 1.0f) * 8191.5f + 8191.5f);
            const int bp = 14 * i;
            if (bp < 64) {
                lo |= code << bp;
                if (bp > 50) hi |= code >> (64 - bp);
            } else {
                hi |= code << (bp - 64);
            }
        }
    }
    uvec4 q;
    q.x = (unsigned)(lo & 0xFFFFFFFFull);
    q.y = (unsigned)(lo >> 32);
    q.z = (unsigned)(hi & 0xFFFFFFFFull);
    q.w = (unsigned)(hi >> 32);
    fn[f] = q;
}

__device__ __forceinline__ float dec14(const unsigned* w, int i) {
    const int bp = 14 * i;
    const int j = bp >> 5;
    const int off = bp & 31;
    unsigned long long u = (unsigned long long)w[j];
    if (j < 3) u |= (unsigned long long)w[j + 1] << 32;
    const unsigned code = (unsigned)(u >> off) & 0x3FFFu;
    return fmaf((float)code, 2.0f / 16383.0f, -1.0f);
}

// ---------------------------------------------------------------------------
// Kernel 2: four threads per pixel (R5 structure), but the random table
// gathers are NON-TEMPORAL: no 64 B L1 line allocation per 16 B record,
// relieving the per-CU L1 miss/fill path that R4==R5 invariance implicated.
// ---------------------------------------------------------------------------
__global__ __launch_bounds__(256) void normal_shader_q14_nt(
    const int*   __restrict__ p2f,    // (N,H,W,K)
    const float* __restrict__ bary,   // (N,H,W,K,3)
    const float* __restrict__ zbuf,   // (N,H,W,K)
    const float* __restrict__ dists,  // (N,H,W,K)
    const uvec4* __restrict__ fn,     // (F) packed face normals
    float*       __restrict__ out)    // (N,H,W,3)
{
    const int t = blockIdx.x * blockDim.x + threadIdx.x;
    const int p = t >> 2;
    const int sub = t & 3;
    if (p >= NPIX) return;

    const int base = p * KF + sub * 2;          // this thread's 2 k-slots

    // ---- issue all independent loads up front ----
    const int2   f2  = *reinterpret_cast<const int2*>(p2f + base);
    const float2 z2  = *reinterpret_cast<const float2*>(zbuf + base);
    const float2 d2  = *reinterpret_cast<const float2*>(dists + base);
    const float2 b01 = *reinterpret_cast<const float2*>(bary + (size_t)base * 3 + 0);
    const float2 b23 = *reinterpret_cast<const float2*>(bary + (size_t)base * 3 + 2);
    const float2 b45 = *reinterpret_cast<const float2*>(bary + (size_t)base * 3 + 4);

    // ---- gathers (depend only on f2), non-temporal: skip L1 line alloc ----
    const int i0 = f2.x < 0 ? 0 : f2.x;
    const int i1 = f2.y < 0 ? 0 : f2.y;
    const uvec4 g0 = __builtin_nontemporal_load(fn + i0);
    const uvec4 g1 = __builtin_nontemporal_load(fn + i1);

    // ---- pass 1: probs, z_inv, quad max ----
    const bool m0 = f2.x >= 0, m1 = f2.y >= 0;
    const float zi0 = m0 ? (ZFAR - z2.x) * (1.0f / (ZFAR - ZNEAR)) : 0.0f;
    const float zi1 = m1 ? (ZFAR - z2.y) * (1.0f / (ZFAR - ZNEAR)) : 0.0f;
    const float pr0 = m0 ? 1.0f / (1.0f + __expf(d2.x * SIGMA_INV)) : 0.0f;
    const float pr1 = m1 ? 1.0f / (1.0f + __expf(d2.y * SIGMA_INV)) : 0.0f;

    float zmax = fmaxf(fmaxf(zi0, zi1), EPSV);
    zmax = fmaxf(zmax, __shfl_xor(zmax, 1));
    zmax = fmaxf(zmax, __shfl_xor(zmax, 2));

    // ---- pass 2: decode + interp + weighted accumulate (2 slots) ----
    float ax, ay, az, wtot;
    {
        unsigned w[4] = { g0.x, g0.y, g0.z, g0.w };
        const float nx = b01.x * dec14(w, 0) + b01.y * dec14(w, 3) + b23.x * dec14(w, 6);
        const float ny = b01.x * dec14(w, 1) + b01.y * dec14(w, 4) + b23.x * dec14(w, 7);
        const float nz = b01.x * dec14(w, 2) + b01.y * dec14(w, 5) + b23.x * dec14(w, 8);
        const float wgt = pr0 * __expf((zi0 - zmax) * GAMMA_INV);
        wtot = wgt;
        ax = wgt * nx; ay = wgt * ny; az = wgt * nz;
    }
    {
        unsigned w[4] = { g1.x, g1.y, g1.z, g1.w };
        const float nx = b23.y * dec14(w, 0) + b45.x * dec14(w, 3) + b45.y * dec14(w, 6);
        const float ny = b23.y * dec14(w, 1) + b45.x * dec14(w, 4) + b45.y * dec14(w, 7);
        const float nz = b23.y * dec14(w, 2) + b45.x * dec14(w, 5) + b45.y * dec14(w, 8);
        const float wgt = pr1 * __expf((zi1 - zmax) * GAMMA_INV);
        wtot += wgt;
        ax = fmaf(wgt, nx, ax); ay = fmaf(wgt, ny, ay); az = fmaf(wgt, nz, az);
    }

    // ---- quad butterfly sum: all 4 lanes end with full-pixel sums ----
    wtot += __shfl_xor(wtot, 1);  wtot += __shfl_xor(wtot, 2);
    ax   += __shfl_xor(ax, 1);    ax   += __shfl_xor(ax, 2);
    ay   += __shfl_xor(ay, 1);    ay   += __shfl_xor(ay, 2);
    az   += __shfl_xor(az, 1);    az   += __shfl_xor(az, 2);

    // ---- epilogue (computed redundantly on all 4 lanes; sub<3 store) ----
    const float delta = fmaxf(__expf((EPSV - zmax) * GAMMA_INV), EPSV);
    const float inv_denom = 1.0f / (wtot + delta);
    const float r = (ax + delta) * inv_denom;   // bg = (1,1,1)
    const float g = (ay + delta) * inv_denom;
    const float b = (az + delta) * inv_denom;

    const float nrm = sqrtf(r * r + g * g + b * b);
    const float invn = 1.0f / fmaxf(nrm, 1e-12f);

    if (sub < 3) {
        const float c = (sub == 0) ? r : (sub == 1) ? g : b;
        out[(size_t)p * 3 + sub] = fmaf(c * invn, 0.5f, 0.5f);
    }
}

// ---------------------------------------------------------------------------
// Fallback (R1 kernel) in case d_ws is too small for the 3.2 MB table.
// ---------------------------------------------------------------------------
__global__ __launch_bounds__(256) void normal_shader_direct(
    const int*   __restrict__ p2f,
    const float* __restrict__ bary,
    const float* __restrict__ zbuf,
    const float* __restrict__ dists,
    const float* __restrict__ vnorm,
    const int*   __restrict__ faces,
    float*       __restrict__ out)
{
    const int p = blockIdx.x * blockDim.x + threadIdx.x;
    if (p >= NPIX) return;

    const int4* pf4 = reinterpret_cast<const int4*>(p2f + (size_t)p * KF);
    int4 fa = pf4[0], fb = pf4[1];
    int f[KF] = {fa.x, fa.y, fa.z, fa.w, fb.x, fb.y, fb.z, fb.w};

    const float4* z4 = reinterpret_cast<const float4*>(zbuf + (size_t)p * KF);
    float4 za = z4[0], zb = z4[1];
    float zv[KF] = {za.x, za.y, za.z, za.w, zb.x, zb.y, zb.z, zb.w};

    const float4* d4 = reinterpret_cast<const float4*>(dists + (size_t)p * KF);
    float4 da = d4[0], db = d4[1];
    float dv[KF] = {da.x, da.y, da.z, da.w, db.x, db.y, db.z, db.w};

    const float4* b4 = reinterpret_cast<const float4*>(bary + (size_t)p * KF * 3);
    float bc[KF * 3];
#pragma unroll
    for (int i = 0; i < 6; ++i) {
        float4 t = b4[i];
        bc[4 * i + 0] = t.x; bc[4 * i + 1] = t.y;
        bc[4 * i + 2] = t.z; bc[4 * i + 3] = t.w;
    }

    float zinv[KF], prob[KF];
    float zmax = EPSV;
#pragma unroll
    for (int k = 0; k < KF; ++k) {
        const bool m = f[k] >= 0;
        const float zi = m ? (ZFAR - zv[k]) * (1.0f / (ZFAR - ZNEAR)) : 0.0f;
        const float pr = m ? 1.0f / (1.0f + __expf(dv[k] * SIGMA_INV)) : 0.0f;
        zinv[k] = zi;
        prob[k] = pr;
        zmax = fmaxf(zmax, zi);
    }

    float accx = 0.0f, accy = 0.0f, accz = 0.0f, wtot = 0.0f;
#pragma unroll
    for (int k = 0; k < KF; ++k) {
        const int idx = f[k] < 0 ? 0 : f[k];
        const int i3 = idx * 3;
        const int v0 = faces[i3 + 0];
        const int v1 = faces[i3 + 1];
        const int v2 = faces[i3 + 2];
        const float b0 = bc[k * 3 + 0];
        const float b1 = bc[k * 3 + 1];
        const float b2 = bc[k * 3 + 2];
        const float* n0 = vnorm + (size_t)v0 * 3;
        const float* n1 = vnorm + (size_t)v1 * 3;
        const float* n2 = vnorm + (size_t)v2 * 3;
        const float nx = b0 * n0[0] + b1 * n1[0] + b2 * n2[0];
        const float ny = b0 * n0[1] + b1 * n1[1] + b2 * n2[1];
        const float nz = b0 * n0[2] + b1 * n1[2] + b2 * n2[2];
        const float wgt = prob[k] * __expf((zinv[k] - zmax) * GAMMA_INV);
        wtot += wgt;
        accx = fmaf(wgt, nx, accx);
        accy = fmaf(wgt, ny, accy);
        accz = fmaf(wgt, nz, accz);
    }

    const float delta = fmaxf(__expf((EPSV - zmax) * GAMMA_INV), EPSV);
    const float inv_denom = 1.0f / (wtot + delta);
    const float r = (accx + delta) * inv_denom;
    const float g = (accy + delta) * inv_denom;
    const float b = (accz + delta) * inv_denom;

    const float nrm = sqrtf(r * r + g * g + b * b);
    const float invn = 1.0f / fmaxf(nrm, 1e-12f);

    float* o = out + (size_t)p * 3;
    o[0] = fmaf(r * invn, 0.5f, 0.5f);
    o[1] = fmaf(g * invn, 0.5f, 0.5f);
    o[2] = fmaf(b * invn, 0.5f, 0.5f);
}

extern "C" void kernel_launch(void* const* d_in, const int* in_sizes, int n_in,
                              void* d_out, int out_size, void* d_ws, size_t ws_size,
                              hipStream_t stream) {
    const int*   p2f   = (const int*)d_in[0];
    const float* bary  = (const float*)d_in[1];
    const float* zbuf  = (const float*)d_in[2];
    const float* dists = (const float*)d_in[3];
    const float* vnorm = (const float*)d_in[4];
    const int*   faces = (const int*)d_in[5];
    float* out = (float*)d_out;

    const int threads = 256;
    const size_t fn_bytes = (size_t)NFACES * sizeof(uvec4);  // 3.2 MB

    if (ws_size >= fn_bytes) {
        uvec4* fn = (uvec4*)d_ws;
        pack_face_normals14<<<(NFACES + threads - 1) / threads, threads, 0, stream>>>(
            faces, vnorm, fn, NFACES);
        const long long nthreads = (long long)NPIX * 4;
        normal_shader_q14_nt<<<(int)((nthreads + threads - 1) / threads), threads, 0, stream>>>(
            p2f, bary, zbuf, dists, fn, out);
    } else {
        normal_shader_direct<<<(NPIX + threads - 1) / threads, threads, 0, stream>>>(
            p2f, bary, zbuf, dists, vnorm, faces, out);
    }
}

// Round 8
// 234.608 us; speedup vs baseline: 1.4781x; 1.4781x over previous
//
#include <hip/hip_runtime.h>

#define SIGMA_INV 1.0e4f          // 1/SIGMA
#define GAMMA_INV 1.0e4f          // 1/GAMMA
#define ZNEAR 1.0f
#define ZFAR 100.0f
#define EPSV 1e-10f

constexpr int KF = 8;
constexpr int NPIX = 4 * 512 * 512;
constexpr int NFACES = 200000;
// exp((zi-zmax)*1e4) < e^-30 ~ 1e-13 is invisible next to surviving weights
// and the 3.9e-3 fp32-vs-ref baseline: skip the gather for those slots.
#define LOG_CUT (-30.0f)

// ---------------------------------------------------------------------------
// Kernel 1: pack the 3 vertex normals of each face into ONE uint4 (16 B).
// 9 components x 14-bit fixed point (126 bits). Half-step err 6.1e-5; the
// final rgb/||rgb|| normalize amplifies ~32x -> ~2e-3, under threshold.
// Table = 3.2 MB -> L2-resident per XCD (R4 FETCH_SIZE confirmed). Plain
// (allocating) loads only: R7 proved nt loads bypass L2 -> 2x slower.
// ---------------------------------------------------------------------------
__global__ __launch_bounds__(256) void pack_face_normals14(
    const int*   __restrict__ faces,   // (F,3)
    const float* __restrict__ vnorm,   // (V,3)
    uint4*       __restrict__ fn,      // (F) packed
    int F)
{
    const int f = blockIdx.x * blockDim.x + threadIdx.x;
    if (f >= F) return;
    const int v[3] = { faces[f * 3 + 0], faces[f * 3 + 1], faces[f * 3 + 2] };

    unsigned long long lo = 0ull, hi = 0ull;
    int i = 0;
#pragma unroll
    for (int t = 0; t < 3; ++t) {
#pragma unroll
        for (int c = 0; c < 3; ++c, ++i) {
            const float x = vnorm[(size_t)v[t] * 3 + c];
            const unsigned long long code = (unsigned long long)(unsigned)
                __float2int_rn(fminf(fmaxf(x, -1.0f), 1.0f) * 8191.5f + 8191.5f);
            const int bp = 14 * i;
            if (bp < 64) {
                lo |= code << bp;
                if (bp > 50) hi |= code >> (64 - bp);
            } else {
                hi |= code << (bp - 64);
            }
        }
    }
    uint4 q;
    q.x = (unsigned)(lo & 0xFFFFFFFFull);
    q.y = (unsigned)(lo >> 32);
    q.z = (unsigned)(hi & 0xFFFFFFFFull);
    q.w = (unsigned)(hi >> 32);
    fn[f] = q;
}

__device__ __forceinline__ float dec14(const unsigned* w, int i) {
    const int bp = 14 * i;
    const int j = bp >> 5;
    const int off = bp & 31;
    unsigned long long u = (unsigned long long)w[j];
    if (j < 3) u |= (unsigned long long)w[j + 1] << 32;
    const unsigned code = (unsigned)(u >> off) & 0x3FFFu;
    return fmaf((float)code, 2.0f / 16383.0f, -1.0f);
}

// ---------------------------------------------------------------------------
// Kernel 2: one thread per pixel (R4 structure) + LAZY GATHER: with
// GAMMA=1e-4 the softmax is ~an argmax over z_inv, so only slots within
// 0.003 of the per-pixel max survive (avg ~1.02 of 8). Gather the face
// record only for surviving slots -> random L2 requests drop ~8x.
// ---------------------------------------------------------------------------
__global__ __launch_bounds__(256) void normal_shader_q14_lazy(
    const int*   __restrict__ p2f,    // (N,H,W,K)
    const float* __restrict__ bary,   // (N,H,W,K,3)
    const float* __restrict__ zbuf,   // (N,H,W,K)
    const float* __restrict__ dists,  // (N,H,W,K)
    const uint4* __restrict__ fn,     // (F) packed face normals
    float*       __restrict__ out)    // (N,H,W,3)
{
    const int p = blockIdx.x * blockDim.x + threadIdx.x;
    if (p >= NPIX) return;

    // ---- coalesced vector loads of per-pixel streams ----
    const int4* pf4 = reinterpret_cast<const int4*>(p2f + (size_t)p * KF);
    int4 fa = pf4[0], fb = pf4[1];
    int f[KF] = {fa.x, fa.y, fa.z, fa.w, fb.x, fb.y, fb.z, fb.w};

    const float4* z4 = reinterpret_cast<const float4*>(zbuf + (size_t)p * KF);
    float4 za = z4[0], zb = z4[1];
    float zv[KF] = {za.x, za.y, za.z, za.w, zb.x, zb.y, zb.z, zb.w};

    const float4* d4 = reinterpret_cast<const float4*>(dists + (size_t)p * KF);
    float4 da = d4[0], db = d4[1];
    float dv[KF] = {da.x, da.y, da.z, da.w, db.x, db.y, db.z, db.w};

    const float4* b4 = reinterpret_cast<const float4*>(bary + (size_t)p * KF * 3);
    float bc[KF * 3];
#pragma unroll
    for (int i = 0; i < 6; ++i) {
        float4 t = b4[i];
        bc[4 * i + 0] = t.x; bc[4 * i + 1] = t.y;
        bc[4 * i + 2] = t.z; bc[4 * i + 3] = t.w;
    }

    // ---- pass 1: probs, z_inv, running max (streams only, no gathers) ----
    float zinv[KF], prob[KF];
    float zmax = EPSV;
#pragma unroll
    for (int k = 0; k < KF; ++k) {
        const bool m = f[k] >= 0;
        const float zi = m ? (ZFAR - zv[k]) * (1.0f / (ZFAR - ZNEAR)) : 0.0f;
        const float pr = m ? 1.0f / (1.0f + __expf(dv[k] * SIGMA_INV)) : 0.0f;
        zinv[k] = zi;
        prob[k] = pr;
        zmax = fmaxf(zmax, zi);
    }

    // ---- pass 2: gather ONLY surviving slots (avg ~1.02 of 8) ----
    float accx = 0.0f, accy = 0.0f, accz = 0.0f, wtot = 0.0f;
#pragma unroll
    for (int k = 0; k < KF; ++k) {
        const float e = (zinv[k] - zmax) * GAMMA_INV;
        if (e > LOG_CUT && prob[k] > 0.0f) {
            const uint4 q = fn[f[k]];           // f[k] >= 0 here (prob>0)
            unsigned w[4] = { q.x, q.y, q.z, q.w };
            const float b0 = bc[k * 3 + 0];
            const float b1 = bc[k * 3 + 1];
            const float b2 = bc[k * 3 + 2];
            const float nx = b0 * dec14(w, 0) + b1 * dec14(w, 3) + b2 * dec14(w, 6);
            const float ny = b0 * dec14(w, 1) + b1 * dec14(w, 4) + b2 * dec14(w, 7);
            const float nz = b0 * dec14(w, 2) + b1 * dec14(w, 5) + b2 * dec14(w, 8);
            const float wgt = prob[k] * __expf(e);
            wtot += wgt;
            accx = fmaf(wgt, nx, accx);
            accy = fmaf(wgt, ny, accy);
            accz = fmaf(wgt, nz, accz);
        }
    }

    const float delta = fmaxf(__expf((EPSV - zmax) * GAMMA_INV), EPSV);
    const float inv_denom = 1.0f / (wtot + delta);
    const float r = (accx + delta) * inv_denom;   // bg = (1,1,1)
    const float g = (accy + delta) * inv_denom;
    const float b = (accz + delta) * inv_denom;

    const float nrm = sqrtf(r * r + g * g + b * b);
    const float invn = 1.0f / fmaxf(nrm, 1e-12f);

    float* o = out + (size_t)p * 3;
    o[0] = fmaf(r * invn, 0.5f, 0.5f);
    o[1] = fmaf(g * invn, 0.5f, 0.5f);
    o[2] = fmaf(b * invn, 0.5f, 0.5f);
}

// ---------------------------------------------------------------------------
// Fallback (R1 kernel) in case d_ws is too small for the 3.2 MB table.
// ---------------------------------------------------------------------------
__global__ __launch_bounds__(256) void normal_shader_direct(
    const int*   __restrict__ p2f,
    const float* __restrict__ bary,
    const float* __restrict__ zbuf,
    const float* __restrict__ dists,
    const float* __restrict__ vnorm,
    const int*   __restrict__ faces,
    float*       __restrict__ out)
{
    const int p = blockIdx.x * blockDim.x + threadIdx.x;
    if (p >= NPIX) return;

    const int4* pf4 = reinterpret_cast<const int4*>(p2f + (size_t)p * KF);
    int4 fa = pf4[0], fb = pf4[1];
    int f[KF] = {fa.x, fa.y, fa.z, fa.w, fb.x, fb.y, fb.z, fb.w};

    const float4* z4 = reinterpret_cast<const float4*>(zbuf + (size_t)p * KF);
    float4 za = z4[0], zb = z4[1];
    float zv[KF] = {za.x, za.y, za.z, za.w, zb.x, zb.y, zb.z, zb.w};

    const float4* d4 = reinterpret_cast<const float4*>(dists + (size_t)p * KF);
    float4 da = d4[0], db = d4[1];
    float dv[KF] = {da.x, da.y, da.z, da.w, db.x, db.y, db.z, db.w};

    const float4* b4 = reinterpret_cast<const float4*>(bary + (size_t)p * KF * 3);
    float bc[KF * 3];
#pragma unroll
    for (int i = 0; i < 6; ++i) {
        float4 t = b4[i];
        bc[4 * i + 0] = t.x; bc[4 * i + 1] = t.y;
        bc[4 * i + 2] = t.z; bc[4 * i + 3] = t.w;
    }

    float zinv[KF], prob[KF];
    float zmax = EPSV;
#pragma unroll
    for (int k = 0; k < KF; ++k) {
        const bool m = f[k] >= 0;
        const float zi = m ? (ZFAR - zv[k]) * (1.0f / (ZFAR - ZNEAR)) : 0.0f;
        const float pr = m ? 1.0f / (1.0f + __expf(dv[k] * SIGMA_INV)) : 0.0f;
        zinv[k] = zi;
        prob[k] = pr;
        zmax = fmaxf(zmax, zi);
    }

    float accx = 0.0f, accy = 0.0f, accz = 0.0f, wtot = 0.0f;
#pragma unroll
    for (int k = 0; k < KF; ++k) {
        const int idx = f[k] < 0 ? 0 : f[k];
        const int i3 = idx * 3;
        const int v0 = faces[i3 + 0];
        const int v1 = faces[i3 + 1];
        const int v2 = faces[i3 + 2];
        const float b0 = bc[k * 3 + 0];
        const float b1 = bc[k * 3 + 1];
        const float b2 = bc[k * 3 + 2];
        const float* n0 = vnorm + (size_t)v0 * 3;
        const float* n1 = vnorm + (size_t)v1 * 3;
        const float* n2 = vnorm + (size_t)v2 * 3;
        const float nx = b0 * n0[0] + b1 * n1[0] + b2 * n2[0];
        const float ny = b0 * n0[1] + b1 * n1[1] + b2 * n2[1];
        const float nz = b0 * n0[2] + b1 * n1[2] + b2 * n2[2];
        const float wgt = prob[k] * __expf((zinv[k] - zmax) * GAMMA_INV);
        wtot += wgt;
        accx = fmaf(wgt, nx, accx);
        accy = fmaf(wgt, ny, accy);
        accz = fmaf(wgt, nz, accz);
    }

    const float delta = fmaxf(__expf((EPSV - zmax) * GAMMA_INV), EPSV);
    const float inv_denom = 1.0f / (wtot + delta);
    const float r = (accx + delta) * inv_denom;
    const float g = (accy + delta) * inv_denom;
    const float b = (accz + delta) * inv_denom;

    const float nrm = sqrtf(r * r + g * g + b * b);
    const float invn = 1.0f / fmaxf(nrm, 1e-12f);

    float* o = out + (size_t)p * 3;
    o[0] = fmaf(r * invn, 0.5f, 0.5f);
    o[1] = fmaf(g * invn, 0.5f, 0.5f);
    o[2] = fmaf(b * invn, 0.5f, 0.5f);
}

extern "C" void kernel_launch(void* const* d_in, const int* in_sizes, int n_in,
                              void* d_out, int out_size, void* d_ws, size_t ws_size,
                              hipStream_t stream) {
    const int*   p2f   = (const int*)d_in[0];
    const float* bary  = (const float*)d_in[1];
    const float* zbuf  = (const float*)d_in[2];
    const float* dists = (const float*)d_in[3];
    const float* vnorm = (const float*)d_in[4];
    const int*   faces = (const int*)d_in[5];
    float* out = (float*)d_out;

    const int threads = 256;
    const size_t fn_bytes = (size_t)NFACES * sizeof(uint4);  // 3.2 MB

    if (ws_size >= fn_bytes) {
        uint4* fn = (uint4*)d_ws;
        pack_face_normals14<<<(NFACES + threads - 1) / threads, threads, 0, stream>>>(
            faces, vnorm, fn, NFACES);
        normal_shader_q14_lazy<<<(NPIX + threads - 1) / threads, threads, 0, stream>>>(
            p2f, bary, zbuf, dists, fn, out);
    } else {
        normal_shader_direct<<<(NPIX + threads - 1) / threads, threads, 0, stream>>>(
            p2f, bary, zbuf, dists, vnorm, faces, out);
    }
}